// Round 2
// baseline (2863.376 us; speedup 1.0000x reference)
//
#include <hip/hip_runtime.h>
#include <cstddef>

// Qwen3.5 MTP layer, MI355X gfx950. Round 1: f32 in/out (per reference dtypes).
// T=2048 H=2048 V=32000 NH=16 NKV=4 DH=128 E=16 K=2 I=1024
// Pre-router GEMMs: split-bf16 (hi+lo) on BOTH operands -> ~2^-17 rel error,
// so router top-2 matches the f32 reference. Post-router MoE: single bf16.

typedef unsigned short u16b;
typedef __attribute__((ext_vector_type(8))) short s8v;   // 8 x bf16 frag
typedef __attribute__((ext_vector_type(4))) float f4v;   // MFMA acc

#define T_TOK 2048
#define HID   2048

__device__ __forceinline__ float bf2f(u16b h) {
  return __uint_as_float(((unsigned int)h) << 16);
}
__device__ __forceinline__ u16b f2bf(float f) {
  unsigned int u = __float_as_uint(f);
  return (u16b)((u + 0x7fffu + ((u >> 16) & 1u)) >> 16);
}
__device__ __forceinline__ void split2(float f, u16b& hi, u16b& lo) {
  hi = f2bf(f);
  lo = f2bf(f - bf2f(hi));
}
__device__ __forceinline__ unsigned long long pack4(const u16b* p) {
  return (unsigned long long)p[0] | ((unsigned long long)p[1] << 16) |
         ((unsigned long long)p[2] << 32) | ((unsigned long long)p[3] << 48);
}
__device__ __forceinline__ f4v mfma_b(s8v a, s8v b, f4v c) {
  return __builtin_amdgcn_mfma_f32_16x16x32_bf16(a, b, c, 0, 0, 0);
}
// block=256 sum-reduce
__device__ __forceinline__ float blk_sum_256(float v, float* lds4) {
  #pragma unroll
  for (int off = 32; off > 0; off >>= 1) v += __shfl_down(v, off);
  int tid = threadIdx.x;
  if ((tid & 63) == 0) lds4[tid >> 6] = v;
  __syncthreads();
  return lds4[0] + lds4[1] + lds4[2] + lds4[3];
}

// ---------------- zero counts ----------------
__global__ void zero_counts_kernel(int* counts) {
  if (threadIdx.x < 16) counts[threadIdx.x] = 0;
}

// ---------------- embed gather + RMS + concat ----------------
__global__ __launch_bounds__(256) void embed_cat_kernel(
    const int* __restrict__ ids, const float* __restrict__ embw,
    const float* __restrict__ hid, const float* __restrict__ w_emb,
    const float* __restrict__ w_hid, float* __restrict__ cat) {
  __shared__ float lds[4];
  int t = blockIdx.x, which = blockIdx.y, tid = threadIdx.x;
  const float* src;
  const float* w;
  float* dst;
  if (which == 0) { src = embw + (size_t)ids[t] * HID; w = w_emb; dst = cat + (size_t)t * 4096; }
  else            { src = hid  + (size_t)t * HID;      w = w_hid; dst = cat + (size_t)t * 4096 + HID; }
  float v[8]; float ss = 0.f;
  #pragma unroll
  for (int i = 0; i < 8; ++i) { v[i] = src[tid + i * 256]; ss += v[i] * v[i]; }
  float tot = blk_sum_256(ss, lds);
  float scale = rsqrtf(tot * (1.f / (float)HID) + 1e-6f);
  #pragma unroll
  for (int i = 0; i < 8; ++i) {
    int j = tid + i * 256;
    dst[j] = v[i] * scale * (1.f + w[j]);
  }
}

// ---------------- RMS norm on f32 rows ----------------
__global__ __launch_bounds__(256) void rms_f32_kernel(
    const float* __restrict__ X, const float* __restrict__ W, float* __restrict__ Y) {
  __shared__ float lds[4];
  int t = blockIdx.x, tid = threadIdx.x;
  const float* row = X + (size_t)t * HID;
  float v[8]; float ss = 0.f;
  #pragma unroll
  for (int i = 0; i < 8; ++i) { v[i] = row[tid + i * 256]; ss += v[i] * v[i]; }
  float tot = blk_sum_256(ss, lds);
  float scale = rsqrtf(tot * (1.f / (float)HID) + 1e-6f);
  float* yrow = Y + (size_t)t * HID;
  #pragma unroll
  for (int i = 0; i < 8; ++i) {
    int j = tid + i * 256;
    yrow[j] = v[i] * scale * (1.f + W[j]);
  }
}

// ---------------- per-head RMS + RoPE (in place) ----------------
__global__ __launch_bounds__(128) void qknorm_rope_kernel(
    float* __restrict__ X, const float* __restrict__ W,
    const int* __restrict__ positions, int ld) {
  __shared__ float wsum[2];
  __shared__ float xs[128];
  __shared__ float sc;
  int t = blockIdx.x, hh = blockIdx.y, d = threadIdx.x;
  float* row = X + (size_t)t * ld + hh * 128;
  float x = row[d];
  float ss = x * x;
  #pragma unroll
  for (int off = 32; off > 0; off >>= 1) ss += __shfl_down(ss, off);
  if ((d & 63) == 0) wsum[d >> 6] = ss;
  __syncthreads();
  if (d == 0) sc = rsqrtf((wsum[0] + wsum[1]) * (1.f / 128.f) + 1e-6f);
  __syncthreads();
  float xn = x * sc * (1.f + W[d]);
  xs[d] = xn;
  __syncthreads();
  int pos = positions[t];
  int i = d & 63;
  // 1/theta^(i/64) = 2^(-i*log2(1e6)/64)
  float invf = exp2f((float)i * (-19.931568569324174f / 64.f));
  float ang = (float)pos * invf;
  float cv = cosf(ang), sv = sinf(ang);
  float other = xs[d ^ 64];
  row[d] = (d < 64) ? (xn * cv - other * sv) : (xn * cv + other * sv);
}

// ---------------- MFMA GEMM (A,B both f32 in memory) ----------------
// MODE 0: C[M,N] = A*B [+ addend]; split-bf16 hi/lo on BOTH A and B (3 MFMAs)
// MODE 1: gathered gate/up (hi only): C h[slot] = silu(g)*u
// MODE 2: gathered down (hi only): C moeout[slot] = acc*gate[slot]
template <int MODE>
__global__ __launch_bounds__(256) void gemm_k(
    const float* __restrict__ A, const float* __restrict__ B,
    const float* __restrict__ B2, float* __restrict__ C,
    const float* __restrict__ addend, const int* __restrict__ counts,
    const int* __restrict__ list, const float* __restrict__ gatebuf,
    int M, int N, int K) {
  __shared__ u16b As[64 * 40];
  __shared__ u16b Al[64 * 40];
  __shared__ u16b Bs[64 * 40];
  __shared__ u16b Bl[64 * 40];
  __shared__ u16b B2s[64 * 40];

  int n0 = blockIdx.x * 64;
  int m0 = blockIdx.y * 64;
  int cnt = M;
  if (MODE != 0) {
    int e = blockIdx.z;
    cnt = counts[e];
    if (m0 >= cnt) return;
    list += e * T_TOK;
    B += (size_t)e * K * N;
    if (MODE == 1) B2 += (size_t)e * K * N;
  }

  int tid = threadIdx.x;
  int wave = tid >> 6, lane = tid & 63;
  int wm = wave >> 1, wn = wave & 1;
  int l16 = lane & 15, quad = lane >> 4;

  int am = tid >> 2, ak = (tid & 3) * 8;      // A stage: 64 rows x 32 k
  int bk = tid >> 3, bn = (tid & 7) * 8;      // B stage: 32 k x 64 n

  const float* aptr;
  if (MODE == 0) {
    aptr = A + (size_t)(m0 + am) * K + ak;
  } else {
    int mr = m0 + am;
    if (mr > cnt - 1) mr = cnt - 1;
    int entry = list[mr];
    int arow = (MODE == 1) ? (entry >> 1) : entry;
    aptr = A + (size_t)arow * K + ak;
  }
  const float* bptr = B + (size_t)bk * N + n0 + bn;
  const float* b2ptr = nullptr;
  if (MODE == 1) b2ptr = B2 + (size_t)bk * N + n0 + bn;

  f4v acc[2][2];
  f4v acc2[2][2];
  #pragma unroll
  for (int i = 0; i < 2; ++i)
    #pragma unroll
    for (int j = 0; j < 2; ++j) { acc[i][j] = (f4v)0.0f; acc2[i][j] = (f4v)0.0f; }

  for (int k0 = 0; k0 < K; k0 += 32) {
    __syncthreads();
    // ---- stage A (f32 -> bf16 hi [+lo]) ----
    {
      const float* ap = aptr + k0;
      float4 f0 = *(const float4*)ap;
      float4 f1 = *(const float4*)(ap + 4);
      float f[8] = {f0.x, f0.y, f0.z, f0.w, f1.x, f1.y, f1.z, f1.w};
      u16b hi[8], lo[8];
      #pragma unroll
      for (int x = 0; x < 8; ++x) {
        split2(f[x], hi[x], lo[x]);
      }
      *(unsigned long long*)&As[am * 40 + ak]     = pack4(hi);
      *(unsigned long long*)&As[am * 40 + ak + 4] = pack4(hi + 4);
      if (MODE == 0) {
        *(unsigned long long*)&Al[am * 40 + ak]     = pack4(lo);
        *(unsigned long long*)&Al[am * 40 + ak + 4] = pack4(lo + 4);
      }
    }
    // ---- stage B transposed: Bs[n][k], f32 -> bf16 hi [+lo] ----
    {
      const float* bp = bptr + (size_t)k0 * N;
      float4 g0 = *(const float4*)bp;
      float4 g1 = *(const float4*)(bp + 4);
      float f[8] = {g0.x, g0.y, g0.z, g0.w, g1.x, g1.y, g1.z, g1.w};
      #pragma unroll
      for (int x = 0; x < 8; ++x) {
        u16b h, l;
        split2(f[x], h, l);
        Bs[(bn + x) * 40 + bk] = h;
        if (MODE == 0) Bl[(bn + x) * 40 + bk] = l;
      }
      if (MODE == 1) {
        const float* cp = b2ptr + (size_t)k0 * N;
        float4 h0 = *(const float4*)cp;
        float4 h1 = *(const float4*)(cp + 4);
        float f2[8] = {h0.x, h0.y, h0.z, h0.w, h1.x, h1.y, h1.z, h1.w};
        #pragma unroll
        for (int x = 0; x < 8; ++x) B2s[(bn + x) * 40 + bk] = f2bf(f2[x]);
      }
    }
    __syncthreads();
    // ---- MFMA: 2x2 16x16 subtiles per wave ----
    s8v a0 = *(const s8v*)&As[(wm * 32 + l16) * 40 + quad * 8];
    s8v a1 = *(const s8v*)&As[(wm * 32 + 16 + l16) * 40 + quad * 8];
    s8v b0 = *(const s8v*)&Bs[(wn * 32 + l16) * 40 + quad * 8];
    s8v b1 = *(const s8v*)&Bs[(wn * 32 + 16 + l16) * 40 + quad * 8];
    acc[0][0] = mfma_b(a0, b0, acc[0][0]);
    acc[0][1] = mfma_b(a0, b1, acc[0][1]);
    acc[1][0] = mfma_b(a1, b0, acc[1][0]);
    acc[1][1] = mfma_b(a1, b1, acc[1][1]);
    if (MODE == 0) {
      s8v a0l = *(const s8v*)&Al[(wm * 32 + l16) * 40 + quad * 8];
      s8v a1l = *(const s8v*)&Al[(wm * 32 + 16 + l16) * 40 + quad * 8];
      s8v b0l = *(const s8v*)&Bl[(wn * 32 + l16) * 40 + quad * 8];
      s8v b1l = *(const s8v*)&Bl[(wn * 32 + 16 + l16) * 40 + quad * 8];
      // a*bl
      acc[0][0] = mfma_b(a0, b0l, acc[0][0]);
      acc[0][1] = mfma_b(a0, b1l, acc[0][1]);
      acc[1][0] = mfma_b(a1, b0l, acc[1][0]);
      acc[1][1] = mfma_b(a1, b1l, acc[1][1]);
      // al*b
      acc[0][0] = mfma_b(a0l, b0, acc[0][0]);
      acc[0][1] = mfma_b(a0l, b1, acc[0][1]);
      acc[1][0] = mfma_b(a1l, b0, acc[1][0]);
      acc[1][1] = mfma_b(a1l, b1, acc[1][1]);
    }
    if (MODE == 1) {
      s8v c0 = *(const s8v*)&B2s[(wn * 32 + l16) * 40 + quad * 8];
      s8v c1 = *(const s8v*)&B2s[(wn * 32 + 16 + l16) * 40 + quad * 8];
      acc2[0][0] = mfma_b(a0, c0, acc2[0][0]);
      acc2[0][1] = mfma_b(a0, c1, acc2[0][1]);
      acc2[1][0] = mfma_b(a1, c0, acc2[1][0]);
      acc2[1][1] = mfma_b(a1, c1, acc2[1][1]);
    }
  }

  // ---- epilogue: D[row=quad*4+r][col=lane&15] ----
  #pragma unroll
  for (int i = 0; i < 2; ++i)
    #pragma unroll
    for (int j = 0; j < 2; ++j)
      #pragma unroll
      for (int r = 0; r < 4; ++r) {
        int mrow = m0 + wm * 32 + i * 16 + quad * 4 + r;
        int col = n0 + wn * 32 + j * 16 + l16;
        float val = acc[i][j][r];
        if (MODE == 0) {
          size_t idx = (size_t)mrow * N + col;
          C[idx] = val + (addend ? addend[idx] : 0.0f);
        } else if (mrow < cnt) {
          int slot = list[mrow];
          if (MODE == 1) {
            float uu = acc2[i][j][r];
            float hv = val / (1.0f + __expf(-val)) * uu;  // silu(g)*u
            C[(size_t)slot * N + col] = hv;
          } else {
            C[(size_t)slot * N + col] = val * gatebuf[slot];
          }
        }
      }
}

// ---------------- flash attention, f32, 32x32 tiles ----------------
__global__ __launch_bounds__(256) void flash_kernel(
    const float* __restrict__ Q, const float* __restrict__ Kb,
    const float* __restrict__ Vb, float* __restrict__ Ob) {
  __shared__ float Qs[32 * 128], Ks[32 * 128], Vs[32 * 128];  // XOR-swizzled
  __shared__ float Ss[32 * 36];
  __shared__ float red[32 * 8];
  __shared__ float mrow[32], lrow[32], arow[32];

  int qt = (gridDim.x - 1) - blockIdx.x;  // big tiles first
  int h = blockIdx.y;
  int g = h >> 2;  // GQA: 4 q-heads per kv-head
  int tid = threadIdx.x;

  // load Q tile
  {
    int row = tid >> 3, d4b = (tid & 7) * 4;
    const float* src = Q + (size_t)(qt * 32 + row) * 2048 + h * 128;
    #pragma unroll
    for (int s = 0; s < 4; ++s) {
      int d4 = d4b + s;
      float4 v = *(const float4*)(src + d4 * 4);
      *(float4*)&Qs[row * 128 + ((d4 ^ row) << 2)] = v;
    }
  }
  if (tid < 32) { mrow[tid] = -1e30f; lrow[tid] = 0.f; }

  float o[2][8];
  #pragma unroll
  for (int i = 0; i < 2; ++i)
    #pragma unroll
    for (int d = 0; d < 8; ++d) o[i][d] = 0.f;

  int ti = tid >> 4, tj = tid & 15;
  int r0 = ti * 2, c0 = tj * 2;
  int sr = tid >> 3, sp = tid & 7;
  int d0 = tj * 8;

  for (int kt = 0; kt <= qt; ++kt) {
    __syncthreads();
    // load K,V tile
    {
      int row = tid >> 3, d4b = (tid & 7) * 4;
      const float* ksrc = Kb + (size_t)(kt * 32 + row) * 512 + g * 128;
      const float* vsrc = Vb + (size_t)(kt * 32 + row) * 512 + g * 128;
      #pragma unroll
      for (int s = 0; s < 4; ++s) {
        int d4 = d4b + s;
        int off = row * 128 + ((d4 ^ row) << 2);
        *(float4*)&Ks[off] = *(const float4*)(ksrc + d4 * 4);
        *(float4*)&Vs[off] = *(const float4*)(vsrc + d4 * 4);
      }
    }
    __syncthreads();
    // S = Q K^T, 2x2 per thread
    float sa00 = 0.f, sa01 = 0.f, sa10 = 0.f, sa11 = 0.f;
    #pragma unroll 8
    for (int d4 = 0; d4 < 32; ++d4) {
      float4 q0 = *(const float4*)&Qs[r0 * 128 + ((d4 ^ r0) << 2)];
      float4 q1 = *(const float4*)&Qs[(r0 + 1) * 128 + ((d4 ^ (r0 + 1)) << 2)];
      float4 k0v = *(const float4*)&Ks[c0 * 128 + ((d4 ^ c0) << 2)];
      float4 k1v = *(const float4*)&Ks[(c0 + 1) * 128 + ((d4 ^ (c0 + 1)) << 2)];
      sa00 += q0.x * k0v.x + q0.y * k0v.y + q0.z * k0v.z + q0.w * k0v.w;
      sa01 += q0.x * k1v.x + q0.y * k1v.y + q0.z * k1v.z + q0.w * k1v.w;
      sa10 += q1.x * k0v.x + q1.y * k0v.y + q1.z * k0v.z + q1.w * k0v.w;
      sa11 += q1.x * k1v.x + q1.y * k1v.y + q1.z * k1v.z + q1.w * k1v.w;
    }
    {
      int qb = qt * 32 + r0, kb = kt * 32 + c0;
      const float sc = 0.08838834764831845f;  // 1/sqrt(128)
      Ss[r0 * 36 + c0]           = (kb     <= qb)     ? sa00 * sc : -1e30f;
      Ss[r0 * 36 + c0 + 1]       = (kb + 1 <= qb)     ? sa01 * sc : -1e30f;
      Ss[(r0 + 1) * 36 + c0]     = (kb     <= qb + 1) ? sa10 * sc : -1e30f;
      Ss[(r0 + 1) * 36 + c0 + 1] = (kb + 1 <= qb + 1) ? sa11 * sc : -1e30f;
    }
    __syncthreads();
    // online softmax
    float mx = -3e38f;
    #pragma unroll
    for (int c = sp * 4; c < sp * 4 + 4; ++c) mx = fmaxf(mx, Ss[sr * 36 + c]);
    red[sr * 8 + sp] = mx;
    __syncthreads();
    if (sp == 0) {
      float mn = mrow[sr];
      #pragma unroll
      for (int p = 0; p < 8; ++p) mn = fmaxf(mn, red[sr * 8 + p]);
      arow[sr] = __expf(mrow[sr] - mn);
      mrow[sr] = mn;
    }
    __syncthreads();
    {
      float m = mrow[sr];
      float sum = 0.f;
      #pragma unroll
      for (int c = sp * 4; c < sp * 4 + 4; ++c) {
        float e2 = __expf(Ss[sr * 36 + c] - m);
        Ss[sr * 36 + c] = e2;
        sum += e2;
      }
      red[sr * 8 + sp] = sum;
    }
    __syncthreads();
    if (sp == 0) {
      float s2 = 0.f;
      #pragma unroll
      for (int p = 0; p < 8; ++p) s2 += red[sr * 8 + p];
      lrow[sr] = lrow[sr] * arow[sr] + s2;
    }
    // PV accumulate
    float a0 = arow[r0], a1 = arow[r0 + 1];
    #pragma unroll
    for (int d = 0; d < 8; ++d) { o[0][d] *= a0; o[1][d] *= a1; }
    #pragma unroll
    for (int c = 0; c < 32; c += 4) {
      float4 p0 = *(const float4*)&Ss[r0 * 36 + c];
      float4 p1 = *(const float4*)&Ss[(r0 + 1) * 36 + c];
      float pc0[4] = {p0.x, p0.y, p0.z, p0.w};
      float pc1[4] = {p1.x, p1.y, p1.z, p1.w};
      #pragma unroll
      for (int cc = 0; cc < 4; ++cc) {
        int vr = c + cc;
        int d4a = d0 >> 2;
        float4 v0 = *(const float4*)&Vs[vr * 128 + ((d4a ^ vr) << 2)];
        float4 v1 = *(const float4*)&Vs[vr * 128 + (((d4a + 1) ^ vr) << 2)];
        float vv[8] = {v0.x, v0.y, v0.z, v0.w, v1.x, v1.y, v1.z, v1.w};
        #pragma unroll
        for (int d = 0; d < 8; ++d) {
          o[0][d] += pc0[cc] * vv[d];
          o[1][d] += pc1[cc] * vv[d];
        }
      }
    }
  }
  __syncthreads();
  float inv0 = 1.f / lrow[r0], inv1 = 1.f / lrow[r0 + 1];
  float* ob0 = Ob + (size_t)(qt * 32 + r0) * 2048 + h * 128 + d0;
  float* ob1 = Ob + (size_t)(qt * 32 + r0 + 1) * 2048 + h * 128 + d0;
  #pragma unroll
  for (int d = 0; d < 8; ++d) {
    ob0[d] = o[0][d] * inv0;
    ob1[d] = o[1][d] * inv1;
  }
}

// ---------------- router: logits (f32 exact), top-2, gates, expert lists ----------------
__global__ __launch_bounds__(256) void router_kernel(
    const float* __restrict__ xn2, const float* __restrict__ rw,
    int* __restrict__ counts, int* __restrict__ list, float* __restrict__ gatebuf) {
  __shared__ float red[256];
  __shared__ float logits[16];
  int t = blockIdx.x, tid = threadIdx.x;
  int e = tid >> 4, p = tid & 15;
  const float* xr = xn2 + (size_t)t * HID;
  float s = 0.f;
  for (int j = p * 128; j < p * 128 + 128; ++j) s += xr[j] * rw[j * 16 + e];
  red[tid] = s;
  __syncthreads();
  if (tid < 16) {
    float l = 0.f;
    #pragma unroll
    for (int p2 = 0; p2 < 16; ++p2) l += red[tid * 16 + p2];
    logits[tid] = l;
  }
  __syncthreads();
  if (tid == 0) {
    int i0 = 0; float l0 = logits[0];
    for (int i = 1; i < 16; ++i) if (logits[i] > l0) { l0 = logits[i]; i0 = i; }
    int i1 = -1; float l1 = -3e38f;
    for (int i = 0; i < 16; ++i) if (i != i0 && logits[i] > l1) { l1 = logits[i]; i1 = i; }
    float g0 = 1.f / (1.f + __expf(l1 - l0));
    float g1 = 1.f - g0;
    int s0 = atomicAdd(&counts[i0], 1);
    list[i0 * T_TOK + s0] = t * 2;
    gatebuf[t * 2] = g0;
    int s1 = atomicAdd(&counts[i1], 1);
    list[i1 * T_TOK + s1] = t * 2 + 1;
    gatebuf[t * 2 + 1] = g1;
  }
}

// ---------------- final: sum expert slots + residual, RMS, f32 out ----------------
__global__ __launch_bounds__(256) void final_kernel(
    const float* __restrict__ moeout, const float* __restrict__ resid,
    const float* __restrict__ W, float* __restrict__ out) {
  __shared__ float lds[4];
  int t = blockIdx.x, tid = threadIdx.x;
  const float* m0 = moeout + (size_t)(2 * t) * HID;
  const float* m1 = moeout + (size_t)(2 * t + 1) * HID;
  const float* rr = resid + (size_t)t * HID;
  float v[8]; float ss = 0.f;
  #pragma unroll
  for (int i = 0; i < 8; ++i) {
    int j = tid + i * 256;
    v[i] = m0[j] + m1[j] + rr[j];
    ss += v[i] * v[i];
  }
  float tot = blk_sum_256(ss, lds);
  float scale = rsqrtf(tot * (1.f / (float)HID) + 1e-6f);
  float* orow = out + (size_t)t * HID;
  #pragma unroll
  for (int i = 0; i < 8; ++i) {
    int j = tid + i * 256;
    orow[j] = v[i] * scale * (1.f + W[j]);
  }
}

extern "C" void kernel_launch(void* const* d_in, const int* in_sizes, int n_in,
                              void* d_out, int out_size, void* d_ws, size_t ws_size,
                              hipStream_t stream) {
  const int* input_ids   = (const int*)d_in[0];
  const int* positions   = (const int*)d_in[1];
  const float* hidden    = (const float*)d_in[2];
  // d_in[3] spec_step_idx: unused by reference
  const float* embed_w   = (const float*)d_in[4];
  const float* fc_w      = (const float*)d_in[5];
  const float* pre_emb   = (const float*)d_in[6];
  const float* pre_hid   = (const float*)d_in[7];
  const float* in_ln     = (const float*)d_in[8];
  const float* post_ln   = (const float*)d_in[9];
  const float* final_w   = (const float*)d_in[10];
  const float* wq        = (const float*)d_in[11];
  const float* wk        = (const float*)d_in[12];
  const float* wv        = (const float*)d_in[13];
  const float* wo        = (const float*)d_in[14];
  const float* qnw       = (const float*)d_in[15];
  const float* knw       = (const float*)d_in[16];
  const float* rw        = (const float*)d_in[17];
  const float* wg        = (const float*)d_in[18];
  const float* wu        = (const float*)d_in[19];
  const float* wd        = (const float*)d_in[20];

  char* ws = (char*)d_ws;
  float* cat    = (float*)(ws + 0);           // 32 MB (T x 4096)
  float* x      = (float*)(ws + 33554432);    // 16 MB fc out / residual1
  float* xn     = (float*)(ws + 50331648);    // 16 MB
  float* q      = (float*)(ws + 67108864);    // 16 MB
  float* kbuf   = (float*)(ws + 83886080);    // 4 MB
  float* vbuf   = (float*)(ws + 88080384);    // 4 MB
  float* attn   = (float*)(ws + 92274688);    // 16 MB
  float* x2     = (float*)(ws + 109051904);   // 16 MB residual2
  float* xn2    = (float*)(ws + 125829120);   // 16 MB
  int*   counts = (int*)(ws + 142606336);     // 64 B
  int*   list   = (int*)(ws + 142606592);     // 128 KB
  float* gateb  = (float*)(ws + 142737664);   // 16 KB
  float* hbuf   = q;    // alias: q dead after attention (4096 x 1024 f32 = 16 MB)
  float* moeout = cat;  // alias: cat dead after fc (4096 x 2048 f32 = 32 MB)

  zero_counts_kernel<<<1, 64, 0, stream>>>(counts);
  embed_cat_kernel<<<dim3(2048, 2), 256, 0, stream>>>(input_ids, embed_w, hidden,
                                                      pre_emb, pre_hid, cat);
  gemm_k<0><<<dim3(32, 32), 256, 0, stream>>>(cat, fc_w, nullptr, x, nullptr,
                                              nullptr, nullptr, nullptr, 2048, 2048, 4096);
  rms_f32_kernel<<<2048, 256, 0, stream>>>(x, in_ln, xn);
  gemm_k<0><<<dim3(32, 32), 256, 0, stream>>>(xn, wq, nullptr, q, nullptr,
                                              nullptr, nullptr, nullptr, 2048, 2048, 2048);
  gemm_k<0><<<dim3(8, 32), 256, 0, stream>>>(xn, wk, nullptr, kbuf, nullptr,
                                             nullptr, nullptr, nullptr, 2048, 512, 2048);
  gemm_k<0><<<dim3(8, 32), 256, 0, stream>>>(xn, wv, nullptr, vbuf, nullptr,
                                             nullptr, nullptr, nullptr, 2048, 512, 2048);
  qknorm_rope_kernel<<<dim3(2048, 16), 128, 0, stream>>>(q, qnw, positions, 2048);
  qknorm_rope_kernel<<<dim3(2048, 4), 128, 0, stream>>>(kbuf, knw, positions, 512);
  flash_kernel<<<dim3(64, 16), 256, 0, stream>>>(q, kbuf, vbuf, attn);
  gemm_k<0><<<dim3(32, 32), 256, 0, stream>>>(attn, wo, nullptr, x2, x,
                                              nullptr, nullptr, nullptr, 2048, 2048, 2048);
  rms_f32_kernel<<<2048, 256, 0, stream>>>(x2, post_ln, xn2);
  router_kernel<<<2048, 256, 0, stream>>>(xn2, rw, counts, list, gateb);
  gemm_k<1><<<dim3(16, 32, 16), 256, 0, stream>>>(xn2, wg, wu, hbuf, nullptr,
                                                  counts, list, nullptr, 0, 1024, 2048);
  gemm_k<2><<<dim3(32, 32, 16), 256, 0, stream>>>(hbuf, wd, nullptr, moeout, nullptr,
                                                  counts, list, gateb, 0, 2048, 1024);
  final_kernel<<<2048, 256, 0, stream>>>(moeout, x2, final_w, (float*)d_out);
}